// Round 10
// baseline (470.551 us; speedup 1.0000x reference)
//
#include <hip/hip_runtime.h>

// ---------------------------------------------------------------------------
// GIN forward: 4x [agg(sum) -> Linear+ReLU -> Linear (+ReLU)] -> mean-pool -> head
// N_NODES=50000, N_EDGES=640000, D=128, N_GRAPHS=64, N_CLASSES=32
// R10: gin_layer back to 256 thr (R8 base) + 4-node interleaved gather
//      (16 loads in flight/wave, was 8; fused-kernel gather is diluted by
//      phase mixing, so per-wave MLP must rise) + R9's direct ds_read hi/lo
//      planes. scanA+scanB merged into ONE decoupled-lookback scan dispatch.
// ---------------------------------------------------------------------------

typedef short short8 __attribute__((ext_vector_type(8)));
typedef float floatx4 __attribute__((ext_vector_type(4)));

#define TM 32
#define ZSTRIDE 136   // shorts/row = 68 words; 16B-aligned rows; 2-way base bank pattern

__device__ __forceinline__ unsigned short f2bf(float x) {
    unsigned int u = __float_as_uint(x);
    u += 0x7fffu + ((u >> 16) & 1u);          // RNE
    return (unsigned short)(u >> 16);
}
__device__ __forceinline__ float bf2f(unsigned short h) {
    return __uint_as_float(((unsigned int)h) << 16);
}

// ---------------- build 1: weight split + dst histogram (independent) --------
// Wf[mat][kc(4)][ct(8)][lane(64)][j(8)] = W[kc*32+(lane>>4)*8+j][ct*16+(lane&15)]

__global__ __launch_bounds__(256) void gin_build1(
    const int* __restrict__ dst, int nEdges, int* __restrict__ counts,
    const float* __restrict__ w1, const float* __restrict__ w2,
    unsigned short* __restrict__ whf, unsigned short* __restrict__ wlf, int wTotal) {
    const int gsize = gridDim.x * 256;
    const int gtid = blockIdx.x * 256 + threadIdx.x;
    for (int idx = gtid; idx < wTotal; idx += gsize) {
        int mat  = idx >> 14;
        int rem  = idx & 16383;
        int kc   = rem >> 12;
        int ct   = (rem >> 9) & 7;
        int lane = (rem >> 3) & 63;
        int j    = rem & 7;
        int row = kc * 32 + (lane >> 4) * 8 + j;
        int col = ct * 16 + (lane & 15);
        int L = mat >> 1;
        const float* W = (mat & 1) ? (w2 + (size_t)L * 16384) : (w1 + (size_t)L * 16384);
        float x = W[row * 128 + col];
        unsigned short h = f2bf(x);
        unsigned short l = f2bf(x - bf2f(h));
        whf[idx] = h;
        wlf[idx] = l;
    }
    for (int i = gtid; i < nEdges; i += gsize) atomicAdd(&counts[dst[i]], 1);
}

// ---------------- build 2: one-dispatch scan (decoupled lookback) ------------
// 196 blocks <= 256 CUs -> all co-resident; lookback waits only on lower ids.
// flags/aggr/prefx pre-zeroed by the memset.

__global__ __launch_bounds__(256) void gin_scan(const int* __restrict__ counts,
                                                int* __restrict__ offsets,
                                                int* __restrict__ cursor,
                                                int* __restrict__ aggr,
                                                int* __restrict__ flags,
                                                int* __restrict__ prefx,
                                                int n, int nEdges) {
    __shared__ int s[256];
    __shared__ int sbase;
    const int t = threadIdx.x, b = blockIdx.x;
    const int i = b * 256 + t;
    int v = (i < n) ? counts[i] : 0;
    s[t] = v;
    __syncthreads();
    for (int off = 1; off < 256; off <<= 1) {
        int u = (t >= off) ? s[t - off] : 0;
        __syncthreads();
        s[t] += u;
        __syncthreads();
    }
    if (t == 0) {
        int total = s[255];
        aggr[b] = total;
        __threadfence();
        atomicExch(&flags[b], 1);           // aggregate ready
        int running = 0;
        for (int j = b - 1; j >= 0; --j) {
            int f;
            do { f = atomicOr(&flags[j], 0); } while (f == 0);
            if (f == 2) { running += atomicOr(&prefx[j], 0); break; }
            running += atomicOr(&aggr[j], 0);
        }
        prefx[b] = running + total;
        __threadfence();
        atomicExch(&flags[b], 2);           // inclusive prefix ready
        sbase = running;
    }
    __syncthreads();
    int base = sbase;
    if (i < n) {
        int o = s[t] - v + base;
        offsets[i] = o;
        cursor[i]  = o;
    }
    if (i == 0) offsets[n] = nEdges;
}

// ---------------- build 3: scatter src ids into CSR order --------------------

__global__ __launch_bounds__(256) void gin_scatter(const int* __restrict__ src,
                                                   const int* __restrict__ dst,
                                                   int nEdges,
                                                   int* __restrict__ cursor,
                                                   int* __restrict__ ssrc) {
    int i = blockIdx.x * 256 + threadIdx.x;
    if (i < nEdges) {
        int p = atomicAdd(&cursor[dst[i]], 1);
        ssrc[p] = src[i];
    }
}

// ---------------- fused layer: agg -> MLP (256 thr, 4-node gather) -----------
// 32-row tile, 4 waves. Wave w gathers rows w*8..w*8+7 as 2 passes of 4 nodes
// interleaved (16 gathers in flight). z / y1 live as bf16 hi & lo LDS planes
// (row-major, stride 136 shorts): MFMA A-fragment = one ds_read_b128.
// Wave w owns coltiles 2w, 2w+1. Last layer pools into gsums (h skips HBM).

__global__ __launch_bounds__(256) void gin_layer(const float* __restrict__ hin,
                                                 const int* __restrict__ offs,
                                                 const int* __restrict__ ssrc,
                                                 const unsigned short* __restrict__ whf,
                                                 const unsigned short* __restrict__ wlf,
                                                 int matBase,
                                                 const float* __restrict__ b1p,
                                                 const float* __restrict__ b2p,
                                                 float* __restrict__ hout,
                                                 const int* __restrict__ batch,
                                                 float* __restrict__ gsums,
                                                 int nNodes, int lastLayer) {
    __shared__ unsigned short smem[2 * TM * ZSTRIDE];   // hi plane, lo plane
    unsigned short* zh = smem;
    unsigned short* zl = smem + TM * ZSTRIDE;
    const int tid = threadIdx.x;
    const int w = tid >> 6, lane = tid & 63;
    const int lo4 = lane & 15, hi4 = lane >> 4;
    const int rowbase = blockIdx.x * TM;

    // ---- gather phase: 2 passes x 4 interleaved nodes (16 loads in flight)
    const float2* h2 = (const float2*)hin;
    const int gbase = rowbase + w * 8;
#pragma unroll
    for (int pp = 0; pp < 2; ++pp) {
        const int n0 = gbase + 4 * pp;
        float2 a[4];
        int e[4], en[4];
#pragma unroll
        for (int q = 0; q < 4; ++q) {
            int n = n0 + q;
            bool ok = n < nNodes;
            a[q] = ok ? h2[(size_t)n * 64 + lane] : make_float2(0.f, 0.f);
            e[q]  = ok ? offs[n] : 0;
            en[q] = ok ? offs[n + 1] : 0;
        }
        // main loop: 16 gathers per iteration
        while (e[0] + 4 <= en[0] && e[1] + 4 <= en[1] &&
               e[2] + 4 <= en[2] && e[3] + 4 <= en[3]) {
            int id[16];
#pragma unroll
            for (int q = 0; q < 4; ++q) {
                id[q * 4 + 0] = ssrc[e[q] + 0];
                id[q * 4 + 1] = ssrc[e[q] + 1];
                id[q * 4 + 2] = ssrc[e[q] + 2];
                id[q * 4 + 3] = ssrc[e[q] + 3];
            }
            float2 v[16];
#pragma unroll
            for (int k = 0; k < 16; ++k) v[k] = h2[(size_t)id[k] * 64 + lane];
#pragma unroll
            for (int q = 0; q < 4; ++q) {
                a[q].x += (v[q*4+0].x + v[q*4+1].x) + (v[q*4+2].x + v[q*4+3].x);
                a[q].y += (v[q*4+0].y + v[q*4+1].y) + (v[q*4+2].y + v[q*4+3].y);
                e[q] += 4;
            }
        }
        // per-node tails
#pragma unroll
        for (int q = 0; q < 4; ++q) {
            for (; e[q] + 4 <= en[q]; e[q] += 4) {
                int s0 = ssrc[e[q]], s1 = ssrc[e[q] + 1];
                int s2 = ssrc[e[q] + 2], s3 = ssrc[e[q] + 3];
                float2 v0 = h2[(size_t)s0 * 64 + lane];
                float2 v1 = h2[(size_t)s1 * 64 + lane];
                float2 v2 = h2[(size_t)s2 * 64 + lane];
                float2 v3 = h2[(size_t)s3 * 64 + lane];
                a[q].x += (v0.x + v1.x) + (v2.x + v3.x);
                a[q].y += (v0.y + v1.y) + (v2.y + v3.y);
            }
            for (; e[q] < en[q]; ++e[q]) {
                float2 vv = h2[(size_t)ssrc[e[q]] * 64 + lane];
                a[q].x += vv.x; a[q].y += vv.y;
            }
        }
        // write z (cols 2*lane, 2*lane+1) as one u32 per plane per row
#pragma unroll
        for (int q = 0; q < 4; ++q) {
            int r = n0 + q - rowbase;
            unsigned short hx = f2bf(a[q].x), hy = f2bf(a[q].y);
            ((unsigned int*)zh)[r * (ZSTRIDE / 2) + lane] =
                (unsigned)hx | ((unsigned)hy << 16);
            ((unsigned int*)zl)[r * (ZSTRIDE / 2) + lane] =
                (unsigned)f2bf(a[q].x - bf2f(hx)) |
                ((unsigned)f2bf(a[q].y - bf2f(hy)) << 16);
        }
    }
    __syncthreads();

    // ---- MLP phase 1: y1 = relu(z @ W1 + b1); wave w owns coltiles 2w,2w+1
    floatx4 acc[2][2];
#pragma unroll
    for (int rg = 0; rg < 2; ++rg)
#pragma unroll
        for (int ct = 0; ct < 2; ++ct) acc[rg][ct] = (floatx4)0.f;

    for (int kc = 0; kc < 4; ++kc) {
        size_t o0 = ((((size_t)matBase * 4 + kc) * 8 + (2 * w)) * 64 + lane) * 8;
        size_t o1 = ((((size_t)matBase * 4 + kc) * 8 + (2 * w + 1)) * 64 + lane) * 8;
        short8 bh0 = *(const short8*)(whf + o0), bl0 = *(const short8*)(wlf + o0);
        short8 bh1 = *(const short8*)(whf + o1), bl1 = *(const short8*)(wlf + o1);
#pragma unroll
        for (int rg = 0; rg < 2; ++rg) {
            const int rbase = (rg * 16 + lo4) * ZSTRIDE + kc * 32 + hi4 * 8;
            short8 ah = *(const short8*)(zh + rbase);
            short8 al = *(const short8*)(zl + rbase);
            acc[rg][0] = __builtin_amdgcn_mfma_f32_16x16x32_bf16(ah, bh0, acc[rg][0], 0, 0, 0);
            acc[rg][0] = __builtin_amdgcn_mfma_f32_16x16x32_bf16(al, bh0, acc[rg][0], 0, 0, 0);
            acc[rg][0] = __builtin_amdgcn_mfma_f32_16x16x32_bf16(ah, bl0, acc[rg][0], 0, 0, 0);
            acc[rg][1] = __builtin_amdgcn_mfma_f32_16x16x32_bf16(ah, bh1, acc[rg][1], 0, 0, 0);
            acc[rg][1] = __builtin_amdgcn_mfma_f32_16x16x32_bf16(al, bh1, acc[rg][1], 0, 0, 0);
            acc[rg][1] = __builtin_amdgcn_mfma_f32_16x16x32_bf16(ah, bl1, acc[rg][1], 0, 0, 0);
        }
    }
    __syncthreads();   // all z reads done; planes reusable for y1

    // epilogue 1: bias + relu + split -> zh/zl (y1)
    float bb1_0 = b1p[w * 32 + lo4];
    float bb1_1 = b1p[w * 32 + 16 + lo4];
#pragma unroll
    for (int rg = 0; rg < 2; ++rg)
#pragma unroll
        for (int ct = 0; ct < 2; ++ct) {
            float bb = ct ? bb1_1 : bb1_0;
#pragma unroll
            for (int r = 0; r < 4; ++r) {
                float v = fmaxf(acc[rg][ct][r] + bb, 0.f);
                unsigned short h = f2bf(v);
                int idx = (rg * 16 + hi4 * 4 + r) * ZSTRIDE + w * 32 + ct * 16 + lo4;
                zh[idx] = h;
                zl[idx] = f2bf(v - bf2f(h));
            }
        }
    __syncthreads();

    // ---- MLP phase 2: h = y1 @ W2 + b2
#pragma unroll
    for (int rg = 0; rg < 2; ++rg)
#pragma unroll
        for (int ct = 0; ct < 2; ++ct) acc[rg][ct] = (floatx4)0.f;

    for (int kc = 0; kc < 4; ++kc) {
        size_t o0 = ((((size_t)(matBase + 1) * 4 + kc) * 8 + (2 * w)) * 64 + lane) * 8;
        size_t o1 = ((((size_t)(matBase + 1) * 4 + kc) * 8 + (2 * w + 1)) * 64 + lane) * 8;
        short8 bh0 = *(const short8*)(whf + o0), bl0 = *(const short8*)(wlf + o0);
        short8 bh1 = *(const short8*)(whf + o1), bl1 = *(const short8*)(wlf + o1);
#pragma unroll
        for (int rg = 0; rg < 2; ++rg) {
            const int rbase = (rg * 16 + lo4) * ZSTRIDE + kc * 32 + hi4 * 8;
            short8 ah = *(const short8*)(zh + rbase);
            short8 al = *(const short8*)(zl + rbase);
            acc[rg][0] = __builtin_amdgcn_mfma_f32_16x16x32_bf16(ah, bh0, acc[rg][0], 0, 0, 0);
            acc[rg][0] = __builtin_amdgcn_mfma_f32_16x16x32_bf16(al, bh0, acc[rg][0], 0, 0, 0);
            acc[rg][0] = __builtin_amdgcn_mfma_f32_16x16x32_bf16(ah, bl0, acc[rg][0], 0, 0, 0);
            acc[rg][1] = __builtin_amdgcn_mfma_f32_16x16x32_bf16(ah, bh1, acc[rg][1], 0, 0, 0);
            acc[rg][1] = __builtin_amdgcn_mfma_f32_16x16x32_bf16(al, bh1, acc[rg][1], 0, 0, 0);
            acc[rg][1] = __builtin_amdgcn_mfma_f32_16x16x32_bf16(ah, bl1, acc[rg][1], 0, 0, 0);
        }
    }

    float bb2_0 = b2p[w * 32 + lo4];
    float bb2_1 = b2p[w * 32 + 16 + lo4];

    if (!lastLayer) {
#pragma unroll
        for (int rg = 0; rg < 2; ++rg)
#pragma unroll
            for (int ct = 0; ct < 2; ++ct) {
                float bb = ct ? bb2_1 : bb2_0;
#pragma unroll
                for (int r = 0; r < 4; ++r) {
                    int row = rowbase + rg * 16 + hi4 * 4 + r;
                    if (row < nNodes) {
                        float v = fmaxf(acc[rg][ct][r] + bb, 0.f);
                        hout[(size_t)row * 128 + w * 32 + ct * 16 + lo4] = v;
                    }
                }
            }
    } else {
        // last layer: no relu; pool tile into gsums (h never hits HBM)
        __syncthreads();   // all y1 reads done; reuse smem as fp32 h (stride 132)
        float* zf = (float*)smem;
#pragma unroll
        for (int rg = 0; rg < 2; ++rg)
#pragma unroll
            for (int ct = 0; ct < 2; ++ct) {
                float bb = ct ? bb2_1 : bb2_0;
#pragma unroll
                for (int r = 0; r < 4; ++r)
                    zf[(rg * 16 + hi4 * 4 + r) * 132 + w * 32 + ct * 16 + lo4] =
                        acc[rg][ct][r] + bb;
            }
        __syncthreads();
        int c = tid & 127, half = tid >> 7;
        int rmax = nNodes - rowbase;
        if (rmax > TM) rmax = TM;
        float accp = 0.f;
        int gcur = -1;
        for (int r = half; r < rmax; r += 2) {
            int g = batch[rowbase + r];
            if (g != gcur) {
                if (gcur >= 0) atomicAdd(&gsums[gcur * 128 + c], accp);
                accp = 0.f;
                gcur = g;
            }
            accp += zf[r * 132 + c];
        }
        if (gcur >= 0) atomicAdd(&gsums[gcur * 128 + c], accp);
    }
}

// ---------------- finalize: divide by count + classifier head ----------------

__device__ __forceinline__ int lb_search(const int* __restrict__ a, int n, int key) {
    int lo = 0, hi = n;
    while (lo < hi) {
        int m = (lo + hi) >> 1;
        if (a[m] < key) lo = m + 1; else hi = m;
    }
    return lo;
}

__global__ __launch_bounds__(128) void gin_pool2(const float* __restrict__ gsums,
                                                 const int* __restrict__ batch, int nNodes,
                                                 const float* __restrict__ wlin,
                                                 const float* __restrict__ blin,
                                                 float* __restrict__ out, int nGraphs) {
    __shared__ float sp[128];
    int g = blockIdx.x;
    int t = threadIdx.x;
    int start = lb_search(batch, nNodes, g);
    int end   = lb_search(batch, nNodes, g + 1);
    float cnt = (float)(end - start);
    float p = gsums[(size_t)g * 128 + t] / fmaxf(cnt, 1.0f);
    out[(size_t)g * 128 + t] = p;
    sp[t] = p;
    __syncthreads();
    if (t < 32) {
        float s = blin[t];
        for (int k = 0; k < 128; ++k) s += sp[k] * wlin[k * 32 + t];
        out[(size_t)nGraphs * 128 + g * 32 + t] = s;
    }
}

// ---------------------------------------------------------------------------

extern "C" void kernel_launch(void* const* d_in, const int* in_sizes, int n_in,
                              void* d_out, int out_size, void* d_ws, size_t ws_size,
                              hipStream_t stream) {
    const float* x     = (const float*)d_in[0];
    const int*   ei    = (const int*)d_in[1];
    const int*   batch = (const int*)d_in[2];
    const float* w1    = (const float*)d_in[3];
    const float* b1    = (const float*)d_in[4];
    const float* w2    = (const float*)d_in[5];
    const float* b2    = (const float*)d_in[6];
    const float* wlin  = (const float*)d_in[7];
    const float* blin  = (const float*)d_in[8];
    float* out = (float*)d_out;

    const int nNodes  = in_sizes[0] / 128;            // 50000
    const int nEdges  = in_sizes[1] / 2;              // 640000
    const int nLayers = in_sizes[3] / (128 * 128);    // 4
    const int nGraphs = out_size / 160;               // 64

    const int* srcArr = ei;
    const int* dstArr = ei + nEdges;

    // workspace layout
    int*   counts   = (int*)d_ws;                 // nNodes
    int*   offsets  = counts + nNodes;            // nNodes + 1
    int*   cursor   = offsets + nNodes + 1;       // nNodes
    int*   aggr     = cursor + nNodes;            // 256
    int*   flags    = aggr + 256;                 // 256
    int*   prefx    = flags + 256;                // 256
    float* gsums    = (float*)(prefx + 256);      // nGraphs * 128
    int*   ssrc     = (int*)(gsums + (size_t)nGraphs * 128);   // nEdges
    size_t zeroWords = (size_t)nNodes * 3 + 1 + 768 + (size_t)nGraphs * 128;

    const int wTotal = nLayers * 2 * 16384;       // frag-ordered split weights
    unsigned short* whf = (unsigned short*)(ssrc + nEdges);    // wTotal
    unsigned short* wlf = whf + (size_t)wTotal;                // wTotal

    size_t byteOff = (size_t)((char*)(wlf + wTotal) - (char*)d_ws);
    byteOff = (byteOff + 63) & ~(size_t)63;
    float* bufA = (float*)((char*)d_ws + byteOff);             // nNodes*128 fp32
    float* bufB = bufA + (size_t)nNodes * 128;                 // nNodes*128 fp32

    hipMemsetAsync(d_ws, 0, zeroWords * sizeof(int), stream);

    const int eb = (nEdges + 255) / 256;
    const int nb = (nNodes + 255) / 256;

    gin_build1<<<eb, 256, 0, stream>>>(dstArr, nEdges, counts, w1, w2, whf, wlf, wTotal);
    gin_scan<<<nb, 256, 0, stream>>>(counts, offsets, cursor, aggr, flags, prefx,
                                     nNodes, nEdges);
    gin_scatter<<<eb, 256, 0, stream>>>(srcArr, dstArr, nEdges, cursor, ssrc);

    const int lb = (nNodes + TM - 1) / TM;
    const float* hin = x;
    float* bufs[2] = {bufA, bufB};
    for (int L = 0; L < nLayers; ++L) {
        int last = (L == nLayers - 1);
        float* hout = bufs[L & 1];
        gin_layer<<<lb, 256, 0, stream>>>(hin, offsets, ssrc, whf, wlf, 2 * L,
                                          b1 + (size_t)L * 128, b2 + (size_t)L * 128,
                                          hout, batch, gsums, nNodes, last);
        hin = hout;
    }
    gin_pool2<<<nGraphs, 128, 0, stream>>>(gsums, batch, nNodes, wlin, blin, out, nGraphs);
}

// Round 11
// 427.730 us; speedup vs baseline: 1.1001x; 1.1001x over previous
//
#include <hip/hip_runtime.h>

// ---------------------------------------------------------------------------
// GIN forward: 4x [agg(sum) -> Linear+ReLU -> Linear (+ReLU)] -> mean-pool -> head
// N_NODES=50000, N_EDGES=640000, D=128, N_GRAPHS=64, N_CLASSES=32
// R11: fused layer at FINER granularity: TM=16, 128-thread blocks (2 waves).
//      Per-wave work identical to R8 (8 gather rows, 48 MFMAs); 3125 blocks
//      -> better CU load balance + gather/MFMA phase mixing (R8's 52% occ /
//      2.87 TB/s was block-imbalance-limited). Gather = R8's 2-node
//      interleave (8 in flight, low VGPR). ds_read_b128 hi/lo planes (R9).
//      Lookback scan (R10) kept.
// ---------------------------------------------------------------------------

typedef short short8 __attribute__((ext_vector_type(8)));
typedef float floatx4 __attribute__((ext_vector_type(4)));

#define TM 16
#define ZSTRIDE 136   // shorts per row (128 + 8 pad); rows 16B-aligned

__device__ __forceinline__ unsigned short f2bf(float x) {
    unsigned int u = __float_as_uint(x);
    u += 0x7fffu + ((u >> 16) & 1u);          // RNE
    return (unsigned short)(u >> 16);
}
__device__ __forceinline__ float bf2f(unsigned short h) {
    return __uint_as_float(((unsigned int)h) << 16);
}

// ---------------- build 1: weight split + dst histogram (independent) --------
// Wf[mat][kc(4)][ct(8)][lane(64)][j(8)] = W[kc*32+(lane>>4)*8+j][ct*16+(lane&15)]

__global__ __launch_bounds__(256) void gin_build1(
    const int* __restrict__ dst, int nEdges, int* __restrict__ counts,
    const float* __restrict__ w1, const float* __restrict__ w2,
    unsigned short* __restrict__ whf, unsigned short* __restrict__ wlf, int wTotal) {
    const int gsize = gridDim.x * 256;
    const int gtid = blockIdx.x * 256 + threadIdx.x;
    for (int idx = gtid; idx < wTotal; idx += gsize) {
        int mat  = idx >> 14;
        int rem  = idx & 16383;
        int kc   = rem >> 12;
        int ct   = (rem >> 9) & 7;
        int lane = (rem >> 3) & 63;
        int j    = rem & 7;
        int row = kc * 32 + (lane >> 4) * 8 + j;
        int col = ct * 16 + (lane & 15);
        int L = mat >> 1;
        const float* W = (mat & 1) ? (w2 + (size_t)L * 16384) : (w1 + (size_t)L * 16384);
        float x = W[row * 128 + col];
        unsigned short h = f2bf(x);
        unsigned short l = f2bf(x - bf2f(h));
        whf[idx] = h;
        wlf[idx] = l;
    }
    for (int i = gtid; i < nEdges; i += gsize) atomicAdd(&counts[dst[i]], 1);
}

// ---------------- build 2: one-dispatch scan (decoupled lookback) ------------

__global__ __launch_bounds__(256) void gin_scan(const int* __restrict__ counts,
                                                int* __restrict__ offsets,
                                                int* __restrict__ cursor,
                                                int* __restrict__ aggr,
                                                int* __restrict__ flags,
                                                int* __restrict__ prefx,
                                                int n, int nEdges) {
    __shared__ int s[256];
    __shared__ int sbase;
    const int t = threadIdx.x, b = blockIdx.x;
    const int i = b * 256 + t;
    int v = (i < n) ? counts[i] : 0;
    s[t] = v;
    __syncthreads();
    for (int off = 1; off < 256; off <<= 1) {
        int u = (t >= off) ? s[t - off] : 0;
        __syncthreads();
        s[t] += u;
        __syncthreads();
    }
    if (t == 0) {
        int total = s[255];
        aggr[b] = total;
        __threadfence();
        atomicExch(&flags[b], 1);
        int running = 0;
        for (int j = b - 1; j >= 0; --j) {
            int f;
            do { f = atomicOr(&flags[j], 0); } while (f == 0);
            if (f == 2) { running += atomicOr(&prefx[j], 0); break; }
            running += atomicOr(&aggr[j], 0);
        }
        prefx[b] = running + total;
        __threadfence();
        atomicExch(&flags[b], 2);
        sbase = running;
    }
    __syncthreads();
    int base = sbase;
    if (i < n) {
        int o = s[t] - v + base;
        offsets[i] = o;
        cursor[i]  = o;
    }
    if (i == 0) offsets[n] = nEdges;
}

// ---------------- build 3: scatter src ids into CSR order --------------------

__global__ __launch_bounds__(256) void gin_scatter(const int* __restrict__ src,
                                                   const int* __restrict__ dst,
                                                   int nEdges,
                                                   int* __restrict__ cursor,
                                                   int* __restrict__ ssrc) {
    int i = blockIdx.x * 256 + threadIdx.x;
    if (i < nEdges) {
        int p = atomicAdd(&cursor[dst[i]], 1);
        ssrc[p] = src[i];
    }
}

// ---------------- fused layer: agg -> MLP (TM=16, 128 thr, 2 waves) ----------
// Wave w gathers rows w*8..w*8+7 (2-node interleave, 8 in flight), then owns
// coltiles w*4..w*4+3 over the single 16-row group. z / y1 live as bf16 hi/lo
// LDS planes (stride 136 shorts): MFMA A-fragment = one ds_read_b128.
// Last layer pools into gsums (h never hits HBM).

__global__ __launch_bounds__(128) void gin_layer(const float* __restrict__ hin,
                                                 const int* __restrict__ offs,
                                                 const int* __restrict__ ssrc,
                                                 const unsigned short* __restrict__ whf,
                                                 const unsigned short* __restrict__ wlf,
                                                 int matBase,
                                                 const float* __restrict__ b1p,
                                                 const float* __restrict__ b2p,
                                                 float* __restrict__ hout,
                                                 const int* __restrict__ batch,
                                                 float* __restrict__ gsums,
                                                 int nNodes, int lastLayer) {
    __shared__ unsigned short smem[2 * TM * ZSTRIDE];   // hi plane, lo plane
    unsigned short* zh = smem;
    unsigned short* zl = smem + TM * ZSTRIDE;
    const int tid = threadIdx.x;
    const int w = tid >> 6, lane = tid & 63;
    const int lo4 = lane & 15, hi4 = lane >> 4;
    const int rowbase = blockIdx.x * TM;

    // ---- gather phase: wave w computes z rows w*8..w*8+7, 2 interleaved
    const float2* h2 = (const float2*)hin;
    const int gbase = rowbase + w * 8;
#pragma unroll
    for (int pp = 0; pp < 4; ++pp) {
        int nA = gbase + 2 * pp, nB = nA + 1;
        bool okA = nA < nNodes, okB = nB < nNodes;
        float2 aA = make_float2(0.f, 0.f), aB = make_float2(0.f, 0.f);
        if (okA) aA = h2[(size_t)nA * 64 + lane];
        if (okB) aB = h2[(size_t)nB * 64 + lane];
        int eA = okA ? offs[nA] : 0, endA = okA ? offs[nA + 1] : 0;
        int eB = okB ? offs[nB] : 0, endB = okB ? offs[nB + 1] : 0;

        while (eA + 4 <= endA && eB + 4 <= endB) {
            int sA0 = ssrc[eA], sA1 = ssrc[eA + 1], sA2 = ssrc[eA + 2], sA3 = ssrc[eA + 3];
            int sB0 = ssrc[eB], sB1 = ssrc[eB + 1], sB2 = ssrc[eB + 2], sB3 = ssrc[eB + 3];
            float2 vA0 = h2[(size_t)sA0 * 64 + lane];
            float2 vA1 = h2[(size_t)sA1 * 64 + lane];
            float2 vA2 = h2[(size_t)sA2 * 64 + lane];
            float2 vA3 = h2[(size_t)sA3 * 64 + lane];
            float2 vB0 = h2[(size_t)sB0 * 64 + lane];
            float2 vB1 = h2[(size_t)sB1 * 64 + lane];
            float2 vB2 = h2[(size_t)sB2 * 64 + lane];
            float2 vB3 = h2[(size_t)sB3 * 64 + lane];
            aA.x += (vA0.x + vA1.x) + (vA2.x + vA3.x);
            aA.y += (vA0.y + vA1.y) + (vA2.y + vA3.y);
            aB.x += (vB0.x + vB1.x) + (vB2.x + vB3.x);
            aB.y += (vB0.y + vB1.y) + (vB2.y + vB3.y);
            eA += 4; eB += 4;
        }
        for (; eA + 4 <= endA; eA += 4) {
            int s0 = ssrc[eA], s1 = ssrc[eA + 1], s2 = ssrc[eA + 2], s3 = ssrc[eA + 3];
            float2 v0 = h2[(size_t)s0 * 64 + lane];
            float2 v1 = h2[(size_t)s1 * 64 + lane];
            float2 v2 = h2[(size_t)s2 * 64 + lane];
            float2 v3 = h2[(size_t)s3 * 64 + lane];
            aA.x += (v0.x + v1.x) + (v2.x + v3.x);
            aA.y += (v0.y + v1.y) + (v2.y + v3.y);
        }
        for (; eA < endA; ++eA) {
            float2 v = h2[(size_t)ssrc[eA] * 64 + lane];
            aA.x += v.x; aA.y += v.y;
        }
        for (; eB + 4 <= endB; eB += 4) {
            int s0 = ssrc[eB], s1 = ssrc[eB + 1], s2 = ssrc[eB + 2], s3 = ssrc[eB + 3];
            float2 v0 = h2[(size_t)s0 * 64 + lane];
            float2 v1 = h2[(size_t)s1 * 64 + lane];
            float2 v2 = h2[(size_t)s2 * 64 + lane];
            float2 v3 = h2[(size_t)s3 * 64 + lane];
            aB.x += (v0.x + v1.x) + (v2.x + v3.x);
            aB.y += (v0.y + v1.y) + (v2.y + v3.y);
        }
        for (; eB < endB; ++eB) {
            float2 v = h2[(size_t)ssrc[eB] * 64 + lane];
            aB.x += v.x; aB.y += v.y;
        }
        // write z (cols 2*lane, 2*lane+1) as one u32 per plane per row
        int rA = nA - rowbase, rB = rA + 1;
        unsigned short hx = f2bf(aA.x), hy = f2bf(aA.y);
        ((unsigned int*)zh)[rA * (ZSTRIDE / 2) + lane] = (unsigned)hx | ((unsigned)hy << 16);
        ((unsigned int*)zl)[rA * (ZSTRIDE / 2) + lane] =
            (unsigned)f2bf(aA.x - bf2f(hx)) | ((unsigned)f2bf(aA.y - bf2f(hy)) << 16);
        hx = f2bf(aB.x); hy = f2bf(aB.y);
        ((unsigned int*)zh)[rB * (ZSTRIDE / 2) + lane] = (unsigned)hx | ((unsigned)hy << 16);
        ((unsigned int*)zl)[rB * (ZSTRIDE / 2) + lane] =
            (unsigned)f2bf(aB.x - bf2f(hx)) | ((unsigned)f2bf(aB.y - bf2f(hy)) << 16);
    }
    __syncthreads();

    // ---- MLP phase 1: y1 = relu(z @ W1 + b1); wave w owns coltiles w*4..w*4+3
    floatx4 acc[4];
#pragma unroll
    for (int ct = 0; ct < 4; ++ct) acc[ct] = (floatx4)0.f;

    for (int kc = 0; kc < 4; ++kc) {
        const int rbase = lo4 * ZSTRIDE + kc * 32 + hi4 * 8;
        short8 ah = *(const short8*)(zh + rbase);
        short8 al = *(const short8*)(zl + rbase);
#pragma unroll
        for (int ct = 0; ct < 4; ++ct) {
            size_t o = ((((size_t)matBase * 4 + kc) * 8 + (w * 4 + ct)) * 64 + lane) * 8;
            short8 bh = *(const short8*)(whf + o);
            short8 bl = *(const short8*)(wlf + o);
            acc[ct] = __builtin_amdgcn_mfma_f32_16x16x32_bf16(ah, bh, acc[ct], 0, 0, 0);
            acc[ct] = __builtin_amdgcn_mfma_f32_16x16x32_bf16(al, bh, acc[ct], 0, 0, 0);
            acc[ct] = __builtin_amdgcn_mfma_f32_16x16x32_bf16(ah, bl, acc[ct], 0, 0, 0);
        }
    }
    __syncthreads();   // all z reads done; planes reusable for y1

    // epilogue 1: bias + relu + split -> zh/zl (y1)
#pragma unroll
    for (int ct = 0; ct < 4; ++ct) {
        float bb = b1p[w * 64 + ct * 16 + lo4];
#pragma unroll
        for (int r = 0; r < 4; ++r) {
            float v = fmaxf(acc[ct][r] + bb, 0.f);
            unsigned short h = f2bf(v);
            int idx = (hi4 * 4 + r) * ZSTRIDE + w * 64 + ct * 16 + lo4;
            zh[idx] = h;
            zl[idx] = f2bf(v - bf2f(h));
        }
    }
    __syncthreads();

    // ---- MLP phase 2: h = y1 @ W2 + b2
#pragma unroll
    for (int ct = 0; ct < 4; ++ct) acc[ct] = (floatx4)0.f;

    for (int kc = 0; kc < 4; ++kc) {
        const int rbase = lo4 * ZSTRIDE + kc * 32 + hi4 * 8;
        short8 ah = *(const short8*)(zh + rbase);
        short8 al = *(const short8*)(zl + rbase);
#pragma unroll
        for (int ct = 0; ct < 4; ++ct) {
            size_t o = ((((size_t)(matBase + 1) * 4 + kc) * 8 + (w * 4 + ct)) * 64 + lane) * 8;
            short8 bh = *(const short8*)(whf + o);
            short8 bl = *(const short8*)(wlf + o);
            acc[ct] = __builtin_amdgcn_mfma_f32_16x16x32_bf16(ah, bh, acc[ct], 0, 0, 0);
            acc[ct] = __builtin_amdgcn_mfma_f32_16x16x32_bf16(al, bh, acc[ct], 0, 0, 0);
            acc[ct] = __builtin_amdgcn_mfma_f32_16x16x32_bf16(ah, bl, acc[ct], 0, 0, 0);
        }
    }

    if (!lastLayer) {
#pragma unroll
        for (int ct = 0; ct < 4; ++ct) {
            float bb = b2p[w * 64 + ct * 16 + lo4];
#pragma unroll
            for (int r = 0; r < 4; ++r) {
                int row = rowbase + hi4 * 4 + r;
                if (row < nNodes) {
                    float v = fmaxf(acc[ct][r] + bb, 0.f);
                    hout[(size_t)row * 128 + w * 64 + ct * 16 + lo4] = v;
                }
            }
        }
    } else {
        // last layer: no relu; pool tile into gsums (h never hits HBM)
        __syncthreads();   // all y1 reads done; reuse smem as fp32 h (stride 132)
        float* zf = (float*)smem;
#pragma unroll
        for (int ct = 0; ct < 4; ++ct) {
            float bb = b2p[w * 64 + ct * 16 + lo4];
#pragma unroll
            for (int r = 0; r < 4; ++r)
                zf[(hi4 * 4 + r) * 132 + w * 64 + ct * 16 + lo4] = acc[ct][r] + bb;
        }
        __syncthreads();
        int c = tid;   // 128 cols, one strip
        int rmax = nNodes - rowbase;
        if (rmax > TM) rmax = TM;
        float accp = 0.f;
        int gcur = -1;
        for (int r = 0; r < rmax; ++r) {
            int g = batch[rowbase + r];
            if (g != gcur) {
                if (gcur >= 0) atomicAdd(&gsums[gcur * 128 + c], accp);
                accp = 0.f;
                gcur = g;
            }
            accp += zf[r * 132 + c];
        }
        if (gcur >= 0) atomicAdd(&gsums[gcur * 128 + c], accp);
    }
}

// ---------------- finalize: divide by count + classifier head ----------------

__device__ __forceinline__ int lb_search(const int* __restrict__ a, int n, int key) {
    int lo = 0, hi = n;
    while (lo < hi) {
        int m = (lo + hi) >> 1;
        if (a[m] < key) lo = m + 1; else hi = m;
    }
    return lo;
}

__global__ __launch_bounds__(128) void gin_pool2(const float* __restrict__ gsums,
                                                 const int* __restrict__ batch, int nNodes,
                                                 const float* __restrict__ wlin,
                                                 const float* __restrict__ blin,
                                                 float* __restrict__ out, int nGraphs) {
    __shared__ float sp[128];
    int g = blockIdx.x;
    int t = threadIdx.x;
    int start = lb_search(batch, nNodes, g);
    int end   = lb_search(batch, nNodes, g + 1);
    float cnt = (float)(end - start);
    float p = gsums[(size_t)g * 128 + t] / fmaxf(cnt, 1.0f);
    out[(size_t)g * 128 + t] = p;
    sp[t] = p;
    __syncthreads();
    if (t < 32) {
        float s = blin[t];
        for (int k = 0; k < 128; ++k) s += sp[k] * wlin[k * 32 + t];
        out[(size_t)nGraphs * 128 + g * 32 + t] = s;
    }
}

// ---------------------------------------------------------------------------

extern "C" void kernel_launch(void* const* d_in, const int* in_sizes, int n_in,
                              void* d_out, int out_size, void* d_ws, size_t ws_size,
                              hipStream_t stream) {
    const float* x     = (const float*)d_in[0];
    const int*   ei    = (const int*)d_in[1];
    const int*   batch = (const int*)d_in[2];
    const float* w1    = (const float*)d_in[3];
    const float* b1    = (const float*)d_in[4];
    const float* w2    = (const float*)d_in[5];
    const float* b2    = (const float*)d_in[6];
    const float* wlin  = (const float*)d_in[7];
    const float* blin  = (const float*)d_in[8];
    float* out = (float*)d_out;

    const int nNodes  = in_sizes[0] / 128;            // 50000
    const int nEdges  = in_sizes[1] / 2;              // 640000
    const int nLayers = in_sizes[3] / (128 * 128);    // 4
    const int nGraphs = out_size / 160;               // 64

    const int* srcArr = ei;
    const int* dstArr = ei + nEdges;

    // workspace layout
    int*   counts   = (int*)d_ws;                 // nNodes
    int*   offsets  = counts + nNodes;            // nNodes + 1
    int*   cursor   = offsets + nNodes + 1;       // nNodes
    int*   aggr     = cursor + nNodes;            // 256
    int*   flags    = aggr + 256;                 // 256
    int*   prefx    = flags + 256;                // 256
    float* gsums    = (float*)(prefx + 256);      // nGraphs * 128
    int*   ssrc     = (int*)(gsums + (size_t)nGraphs * 128);   // nEdges
    size_t zeroWords = (size_t)nNodes * 3 + 1 + 768 + (size_t)nGraphs * 128;

    const int wTotal = nLayers * 2 * 16384;       // frag-ordered split weights
    unsigned short* whf = (unsigned short*)(ssrc + nEdges);    // wTotal
    unsigned short* wlf = whf + (size_t)wTotal;                // wTotal

    size_t byteOff = (size_t)((char*)(wlf + wTotal) - (char*)d_ws);
    byteOff = (byteOff + 63) & ~(size_t)63;
    float* bufA = (float*)((char*)d_ws + byteOff);             // nNodes*128 fp32
    float* bufB = bufA + (size_t)nNodes * 128;                 // nNodes*128 fp32

    hipMemsetAsync(d_ws, 0, zeroWords * sizeof(int), stream);

    const int eb = (nEdges + 255) / 256;
    const int nb = (nNodes + 255) / 256;

    gin_build1<<<eb, 256, 0, stream>>>(dstArr, nEdges, counts, w1, w2, whf, wlf, wTotal);
    gin_scan<<<nb, 256, 0, stream>>>(counts, offsets, cursor, aggr, flags, prefx,
                                     nNodes, nEdges);
    gin_scatter<<<eb, 256, 0, stream>>>(srcArr, dstArr, nEdges, cursor, ssrc);

    const int lb = (nNodes + TM - 1) / TM;
    const float* hin = x;
    float* bufs[2] = {bufA, bufB};
    for (int L = 0; L < nLayers; ++L) {
        int last = (L == nLayers - 1);
        float* hout = bufs[L & 1];
        gin_layer<<<lb, 128, 0, stream>>>(hin, offsets, ssrc, whf, wlf, 2 * L,
                                          b1 + (size_t)L * 128, b2 + (size_t)L * 128,
                                          hout, batch, gsums, nNodes, last);
        hin = hout;
    }
    gin_pool2<<<nGraphs, 128, 0, stream>>>(gsums, batch, nNodes, wlin, blin, out, nGraphs);
}

// Round 12
// 393.232 us; speedup vs baseline: 1.1966x; 1.0877x over previous
//
#include <hip/hip_runtime.h>

// ---------------------------------------------------------------------------
// GIN forward: 4x [agg(sum) -> Linear+ReLU -> Linear (+ReLU)] -> mean-pool -> head
// N_NODES=50000, N_EDGES=640000, D=128, N_GRAPHS=64, N_CLASSES=32
// R12: exact R8 structure (best total, 394us: TM=32/256thr fused layer,
//      scanA+scanB) + two VALU cuts on the gather critical path:
//      (1) 32-bit offset addressing (base + (id<<9) + lane*8) -> 1 VALU/load
//      (2) hi/lo bf16 LDS planes (ds_read_b128 A-frags, no unpack VALU).
// ---------------------------------------------------------------------------

typedef short short8 __attribute__((ext_vector_type(8)));
typedef float floatx4 __attribute__((ext_vector_type(4)));

#define TM 32
#define ZSTRIDE 136   // shorts per row (128 + 8 pad); rows 16B-aligned

__device__ __forceinline__ unsigned short f2bf(float x) {
    unsigned int u = __float_as_uint(x);
    u += 0x7fffu + ((u >> 16) & 1u);          // RNE
    return (unsigned short)(u >> 16);
}
__device__ __forceinline__ float bf2f(unsigned short h) {
    return __uint_as_float(((unsigned int)h) << 16);
}

// 32-bit-offset row load: h row id, this lane's 8-byte slice
__device__ __forceinline__ float2 ldrow(const char* __restrict__ base,
                                        int id, unsigned laneoff) {
    return *(const float2*)(base + ((unsigned)id << 9) + laneoff);
}

// ---------------- build 1: weight split + dst histogram (independent) --------
// Wf[mat][kc(4)][ct(8)][lane(64)][j(8)] = W[kc*32+(lane>>4)*8+j][ct*16+(lane&15)]

__global__ __launch_bounds__(256) void gin_build1(
    const int* __restrict__ dst, int nEdges, int* __restrict__ counts,
    const float* __restrict__ w1, const float* __restrict__ w2,
    unsigned short* __restrict__ whf, unsigned short* __restrict__ wlf, int wTotal) {
    const int gsize = gridDim.x * 256;
    const int gtid = blockIdx.x * 256 + threadIdx.x;
    for (int idx = gtid; idx < wTotal; idx += gsize) {
        int mat  = idx >> 14;
        int rem  = idx & 16383;
        int kc   = rem >> 12;
        int ct   = (rem >> 9) & 7;
        int lane = (rem >> 3) & 63;
        int j    = rem & 7;
        int row = kc * 32 + (lane >> 4) * 8 + j;
        int col = ct * 16 + (lane & 15);
        int L = mat >> 1;
        const float* W = (mat & 1) ? (w2 + (size_t)L * 16384) : (w1 + (size_t)L * 16384);
        float x = W[row * 128 + col];
        unsigned short h = f2bf(x);
        unsigned short l = f2bf(x - bf2f(h));
        whf[idx] = h;
        wlf[idx] = l;
    }
    for (int i = gtid; i < nEdges; i += gsize) atomicAdd(&counts[dst[i]], 1);
}

// ---------------- build 2a: per-chunk exclusive scan (chunk = 256) -----------

__global__ __launch_bounds__(256) void gin_scanA(const int* __restrict__ counts,
                                                 int* __restrict__ offsets,
                                                 int* __restrict__ partials, int n) {
    __shared__ int s[256];
    int t = threadIdx.x;
    int i = blockIdx.x * 256 + t;
    int v = (i < n) ? counts[i] : 0;
    s[t] = v;
    __syncthreads();
    for (int off = 1; off < 256; off <<= 1) {
        int u = (t >= off) ? s[t - off] : 0;
        __syncthreads();
        s[t] += u;
        __syncthreads();
    }
    if (i < n) offsets[i] = s[t] - v;          // block-local exclusive
    if (t == 255) partials[blockIdx.x] = s[255];
}

// ---------------- build 2b: add chunk bases (each block re-scans partials) ---

__global__ __launch_bounds__(256) void gin_scanB(int* __restrict__ offsets,
                                                 const int* __restrict__ partials,
                                                 int* __restrict__ cursor,
                                                 int nb, int n, int nEdges) {
    __shared__ int s[256];
    int t = threadIdx.x;
    s[t] = (t < nb) ? partials[t] : 0;
    __syncthreads();
    for (int off = 1; off < 256; off <<= 1) {
        int u = (t >= off) ? s[t - off] : 0;
        __syncthreads();
        s[t] += u;
        __syncthreads();
    }
    int base = (blockIdx.x > 0) ? s[blockIdx.x - 1] : 0;   // inclusive[b-1]
    int i = blockIdx.x * 256 + t;
    if (i < n) {
        int o = offsets[i] + base;
        offsets[i] = o;
        cursor[i]  = o;
    }
    if (i == 0) offsets[n] = nEdges;
}

// ---------------- build 3: scatter src ids into CSR order --------------------

__global__ __launch_bounds__(256) void gin_scatter(const int* __restrict__ src,
                                                   const int* __restrict__ dst,
                                                   int nEdges,
                                                   int* __restrict__ cursor,
                                                   int* __restrict__ ssrc) {
    int i = blockIdx.x * 256 + threadIdx.x;
    if (i < nEdges) {
        int p = atomicAdd(&cursor[dst[i]], 1);
        ssrc[p] = src[i];
    }
}

// ---------------- fused layer: agg -> MLP (TM=32, 256 thr, 4 waves) ----------
// Wave w gathers rows w*8..w*8+7 (2-node interleave, 8 gathers in flight,
// 32-bit offset addressing), then owns coltiles 2w,2w+1 over both rowgroups.
// z / y1 live as bf16 hi/lo LDS planes (stride 136 shorts): A-frag = one
// ds_read_b128. Last layer pools into gsums (h never hits HBM).

__global__ __launch_bounds__(256) void gin_layer(const float* __restrict__ hin,
                                                 const int* __restrict__ offs,
                                                 const int* __restrict__ ssrc,
                                                 const unsigned short* __restrict__ whf,
                                                 const unsigned short* __restrict__ wlf,
                                                 int matBase,
                                                 const float* __restrict__ b1p,
                                                 const float* __restrict__ b2p,
                                                 float* __restrict__ hout,
                                                 const int* __restrict__ batch,
                                                 float* __restrict__ gsums,
                                                 int nNodes, int lastLayer) {
    __shared__ unsigned short smem[2 * TM * ZSTRIDE];   // hi plane, lo plane
    unsigned short* zh = smem;
    unsigned short* zl = smem + TM * ZSTRIDE;
    const int tid = threadIdx.x;
    const int w = tid >> 6, lane = tid & 63;
    const int lo4 = lane & 15, hi4 = lane >> 4;
    const int rowbase = blockIdx.x * TM;
    const char* hbase = (const char*)hin;
    const unsigned laneoff = (unsigned)lane * 8u;

    // ---- gather phase: wave w computes z rows w*8..w*8+7, 2 interleaved
    const int gbase = rowbase + w * 8;
#pragma unroll
    for (int pp = 0; pp < 4; ++pp) {
        int nA = gbase + 2 * pp, nB = nA + 1;
        bool okA = nA < nNodes, okB = nB < nNodes;
        float2 aA = make_float2(0.f, 0.f), aB = make_float2(0.f, 0.f);
        if (okA) aA = ldrow(hbase, nA, laneoff);
        if (okB) aB = ldrow(hbase, nB, laneoff);
        int eA = okA ? offs[nA] : 0, endA = okA ? offs[nA + 1] : 0;
        int eB = okB ? offs[nB] : 0, endB = okB ? offs[nB + 1] : 0;

        while (eA + 4 <= endA && eB + 4 <= endB) {
            int sA0 = ssrc[eA], sA1 = ssrc[eA + 1], sA2 = ssrc[eA + 2], sA3 = ssrc[eA + 3];
            int sB0 = ssrc[eB], sB1 = ssrc[eB + 1], sB2 = ssrc[eB + 2], sB3 = ssrc[eB + 3];
            float2 vA0 = ldrow(hbase, sA0, laneoff);
            float2 vA1 = ldrow(hbase, sA1, laneoff);
            float2 vA2 = ldrow(hbase, sA2, laneoff);
            float2 vA3 = ldrow(hbase, sA3, laneoff);
            float2 vB0 = ldrow(hbase, sB0, laneoff);
            float2 vB1 = ldrow(hbase, sB1, laneoff);
            float2 vB2 = ldrow(hbase, sB2, laneoff);
            float2 vB3 = ldrow(hbase, sB3, laneoff);
            aA.x += (vA0.x + vA1.x) + (vA2.x + vA3.x);
            aA.y += (vA0.y + vA1.y) + (vA2.y + vA3.y);
            aB.x += (vB0.x + vB1.x) + (vB2.x + vB3.x);
            aB.y += (vB0.y + vB1.y) + (vB2.y + vB3.y);
            eA += 4; eB += 4;
        }
        for (; eA + 4 <= endA; eA += 4) {
            int s0 = ssrc[eA], s1 = ssrc[eA + 1], s2 = ssrc[eA + 2], s3 = ssrc[eA + 3];
            float2 v0 = ldrow(hbase, s0, laneoff);
            float2 v1 = ldrow(hbase, s1, laneoff);
            float2 v2 = ldrow(hbase, s2, laneoff);
            float2 v3 = ldrow(hbase, s3, laneoff);
            aA.x += (v0.x + v1.x) + (v2.x + v3.x);
            aA.y += (v0.y + v1.y) + (v2.y + v3.y);
        }
        for (; eA < endA; ++eA) {
            float2 v = ldrow(hbase, ssrc[eA], laneoff);
            aA.x += v.x; aA.y += v.y;
        }
        for (; eB + 4 <= endB; eB += 4) {
            int s0 = ssrc[eB], s1 = ssrc[eB + 1], s2 = ssrc[eB + 2], s3 = ssrc[eB + 3];
            float2 v0 = ldrow(hbase, s0, laneoff);
            float2 v1 = ldrow(hbase, s1, laneoff);
            float2 v2 = ldrow(hbase, s2, laneoff);
            float2 v3 = ldrow(hbase, s3, laneoff);
            aB.x += (v0.x + v1.x) + (v2.x + v3.x);
            aB.y += (v0.y + v1.y) + (v2.y + v3.y);
        }
        for (; eB < endB; ++eB) {
            float2 v = ldrow(hbase, ssrc[eB], laneoff);
            aB.x += v.x; aB.y += v.y;
        }
        // write z (cols 2*lane, 2*lane+1) as one u32 per plane per row
        int rA = nA - rowbase, rB = rA + 1;
        unsigned short hx = f2bf(aA.x), hy = f2bf(aA.y);
        ((unsigned int*)zh)[rA * (ZSTRIDE / 2) + lane] = (unsigned)hx | ((unsigned)hy << 16);
        ((unsigned int*)zl)[rA * (ZSTRIDE / 2) + lane] =
            (unsigned)f2bf(aA.x - bf2f(hx)) | ((unsigned)f2bf(aA.y - bf2f(hy)) << 16);
        hx = f2bf(aB.x); hy = f2bf(aB.y);
        ((unsigned int*)zh)[rB * (ZSTRIDE / 2) + lane] = (unsigned)hx | ((unsigned)hy << 16);
        ((unsigned int*)zl)[rB * (ZSTRIDE / 2) + lane] =
            (unsigned)f2bf(aB.x - bf2f(hx)) | ((unsigned)f2bf(aB.y - bf2f(hy)) << 16);
    }
    __syncthreads();

    // ---- MLP phase 1: y1 = relu(z @ W1 + b1); wave w owns coltiles 2w,2w+1
    floatx4 acc[2][2];
#pragma unroll
    for (int rg = 0; rg < 2; ++rg)
#pragma unroll
        for (int ct = 0; ct < 2; ++ct) acc[rg][ct] = (floatx4)0.f;

    for (int kc = 0; kc < 4; ++kc) {
        size_t o0 = ((((size_t)matBase * 4 + kc) * 8 + (2 * w)) * 64 + lane) * 8;
        size_t o1 = ((((size_t)matBase * 4 + kc) * 8 + (2 * w + 1)) * 64 + lane) * 8;
        short8 bh0 = *(const short8*)(whf + o0), bl0 = *(const short8*)(wlf + o0);
        short8 bh1 = *(const short8*)(whf + o1), bl1 = *(const short8*)(wlf + o1);
#pragma unroll
        for (int rg = 0; rg < 2; ++rg) {
            const int rbase = (rg * 16 + lo4) * ZSTRIDE + kc * 32 + hi4 * 8;
            short8 ah = *(const short8*)(zh + rbase);
            short8 al = *(const short8*)(zl + rbase);
            acc[rg][0] = __builtin_amdgcn_mfma_f32_16x16x32_bf16(ah, bh0, acc[rg][0], 0, 0, 0);
            acc[rg][0] = __builtin_amdgcn_mfma_f32_16x16x32_bf16(al, bh0, acc[rg][0], 0, 0, 0);
            acc[rg][0] = __builtin_amdgcn_mfma_f32_16x16x32_bf16(ah, bl0, acc[rg][0], 0, 0, 0);
            acc[rg][1] = __builtin_amdgcn_mfma_f32_16x16x32_bf16(ah, bh1, acc[rg][1], 0, 0, 0);
            acc[rg][1] = __builtin_amdgcn_mfma_f32_16x16x32_bf16(al, bh1, acc[rg][1], 0, 0, 0);
            acc[rg][1] = __builtin_amdgcn_mfma_f32_16x16x32_bf16(ah, bl1, acc[rg][1], 0, 0, 0);
        }
    }
    __syncthreads();   // all z reads done; planes reusable for y1

    // epilogue 1: bias + relu + split -> zh/zl (y1)
    float bb1_0 = b1p[w * 32 + lo4];
    float bb1_1 = b1p[w * 32 + 16 + lo4];
#pragma unroll
    for (int rg = 0; rg < 2; ++rg)
#pragma unroll
        for (int ct = 0; ct < 2; ++ct) {
            float bb = ct ? bb1_1 : bb1_0;
#pragma unroll
            for (int r = 0; r < 4; ++r) {
                float v = fmaxf(acc[rg][ct][r] + bb, 0.f);
                unsigned short h = f2bf(v);
                int idx = (rg * 16 + hi4 * 4 + r) * ZSTRIDE + w * 32 + ct * 16 + lo4;
                zh[idx] = h;
                zl[idx] = f2bf(v - bf2f(h));
            }
        }
    __syncthreads();

    // ---- MLP phase 2: h = y1 @ W2 + b2
#pragma unroll
    for (int rg = 0; rg < 2; ++rg)
#pragma unroll
        for (int ct = 0; ct < 2; ++ct) acc[rg][ct] = (floatx4)0.f;

    for (int kc = 0; kc < 4; ++kc) {
        size_t o0 = ((((size_t)(matBase + 1) * 4 + kc) * 8 + (2 * w)) * 64 + lane) * 8;
        size_t o1 = ((((size_t)(matBase + 1) * 4 + kc) * 8 + (2 * w + 1)) * 64 + lane) * 8;
        short8 bh0 = *(const short8*)(whf + o0), bl0 = *(const short8*)(wlf + o0);
        short8 bh1 = *(const short8*)(whf + o1), bl1 = *(const short8*)(wlf + o1);
#pragma unroll
        for (int rg = 0; rg < 2; ++rg) {
            const int rbase = (rg * 16 + lo4) * ZSTRIDE + kc * 32 + hi4 * 8;
            short8 ah = *(const short8*)(zh + rbase);
            short8 al = *(const short8*)(zl + rbase);
            acc[rg][0] = __builtin_amdgcn_mfma_f32_16x16x32_bf16(ah, bh0, acc[rg][0], 0, 0, 0);
            acc[rg][0] = __builtin_amdgcn_mfma_f32_16x16x32_bf16(al, bh0, acc[rg][0], 0, 0, 0);
            acc[rg][0] = __builtin_amdgcn_mfma_f32_16x16x32_bf16(ah, bl0, acc[rg][0], 0, 0, 0);
            acc[rg][1] = __builtin_amdgcn_mfma_f32_16x16x32_bf16(ah, bh1, acc[rg][1], 0, 0, 0);
            acc[rg][1] = __builtin_amdgcn_mfma_f32_16x16x32_bf16(al, bh1, acc[rg][1], 0, 0, 0);
            acc[rg][1] = __builtin_amdgcn_mfma_f32_16x16x32_bf16(ah, bl1, acc[rg][1], 0, 0, 0);
        }
    }

    float bb2_0 = b2p[w * 32 + lo4];
    float bb2_1 = b2p[w * 32 + 16 + lo4];

    if (!lastLayer) {
#pragma unroll
        for (int rg = 0; rg < 2; ++rg)
#pragma unroll
            for (int ct = 0; ct < 2; ++ct) {
                float bb = ct ? bb2_1 : bb2_0;
#pragma unroll
                for (int r = 0; r < 4; ++r) {
                    int row = rowbase + rg * 16 + hi4 * 4 + r;
                    if (row < nNodes) {
                        float v = fmaxf(acc[rg][ct][r] + bb, 0.f);
                        hout[(size_t)row * 128 + w * 32 + ct * 16 + lo4] = v;
                    }
                }
            }
    } else {
        // last layer: no relu; pool tile into gsums (h never hits HBM)
        __syncthreads();   // all y1 reads done; reuse smem as fp32 h (stride 132)
        float* zf = (float*)smem;
#pragma unroll
        for (int rg = 0; rg < 2; ++rg)
#pragma unroll
            for (int ct = 0; ct < 2; ++ct) {
                float bb = ct ? bb2_1 : bb2_0;
#pragma unroll
                for (int r = 0; r < 4; ++r)
                    zf[(rg * 16 + hi4 * 4 + r) * 132 + w * 32 + ct * 16 + lo4] =
                        acc[rg][ct][r] + bb;
            }
        __syncthreads();
        int c = tid & 127, half = tid >> 7;
        int rmax = nNodes - rowbase;
        if (rmax > TM) rmax = TM;
        float accp = 0.f;
        int gcur = -1;
        for (int r = half; r < rmax; r += 2) {
            int g = batch[rowbase + r];
            if (g != gcur) {
                if (gcur >= 0) atomicAdd(&gsums[gcur * 128 + c], accp);
                accp = 0.f;
                gcur = g;
            }
            accp += zf[r * 132 + c];
        }
        if (gcur >= 0) atomicAdd(&gsums[gcur * 128 + c], accp);
    }
}

// ---------------- finalize: divide by count + classifier head ----------------

__device__ __forceinline__ int lb_search(const int* __restrict__ a, int n, int key) {
    int lo = 0, hi = n;
    while (lo < hi) {
        int m = (lo + hi) >> 1;
        if (a[m] < key) lo = m + 1; else hi = m;
    }
    return lo;
}

__global__ __launch_bounds__(128) void gin_pool2(const float* __restrict__ gsums,
                                                 const int* __restrict__ batch, int nNodes,
                                                 const float* __restrict__ wlin,
                                                 const float* __restrict__ blin,
                                                 float* __restrict__ out, int nGraphs) {
    __shared__ float sp[128];
    int g = blockIdx.x;
    int t = threadIdx.x;
    int start = lb_search(batch, nNodes, g);
    int end   = lb_search(batch, nNodes, g + 1);
    float cnt = (float)(end - start);
    float p = gsums[(size_t)g * 128 + t] / fmaxf(cnt, 1.0f);
    out[(size_t)g * 128 + t] = p;
    sp[t] = p;
    __syncthreads();
    if (t < 32) {
        float s = blin[t];
        for (int k = 0; k < 128; ++k) s += sp[k] * wlin[k * 32 + t];
        out[(size_t)nGraphs * 128 + g * 32 + t] = s;
    }
}

// ---------------------------------------------------------------------------

extern "C" void kernel_launch(void* const* d_in, const int* in_sizes, int n_in,
                              void* d_out, int out_size, void* d_ws, size_t ws_size,
                              hipStream_t stream) {
    const float* x     = (const float*)d_in[0];
    const int*   ei    = (const int*)d_in[1];
    const int*   batch = (const int*)d_in[2];
    const float* w1    = (const float*)d_in[3];
    const float* b1    = (const float*)d_in[4];
    const float* w2    = (const float*)d_in[5];
    const float* b2    = (const float*)d_in[6];
    const float* wlin  = (const float*)d_in[7];
    const float* blin  = (const float*)d_in[8];
    float* out = (float*)d_out;

    const int nNodes  = in_sizes[0] / 128;            // 50000
    const int nEdges  = in_sizes[1] / 2;              // 640000
    const int nLayers = in_sizes[3] / (128 * 128);    // 4
    const int nGraphs = out_size / 160;               // 64

    const int* srcArr = ei;
    const int* dstArr = ei + nEdges;

    // workspace layout
    int*   counts   = (int*)d_ws;                 // nNodes
    int*   offsets  = counts + nNodes;            // nNodes + 1
    int*   cursor   = offsets + nNodes + 1;       // nNodes
    int*   partials = cursor + nNodes;            // 256
    float* gsums    = (float*)(partials + 256);   // nGraphs * 128
    int*   ssrc     = (int*)(gsums + (size_t)nGraphs * 128);   // nEdges
    size_t zeroWords = (size_t)nNodes * 3 + 1 + 256 + (size_t)nGraphs * 128;

    const int wTotal = nLayers * 2 * 16384;       // frag-ordered split weights
    unsigned short* whf = (unsigned short*)(ssrc + nEdges);    // wTotal
    unsigned short* wlf = whf + (size_t)wTotal;                // wTotal

    size_t byteOff = (size_t)((char*)(wlf + wTotal) - (char*)d_ws);
    byteOff = (byteOff + 63) & ~(size_t)63;
    float* bufA = (float*)((char*)d_ws + byteOff);             // nNodes*128 fp32
    float* bufB = bufA + (size_t)nNodes * 128;                 // nNodes*128 fp32

    hipMemsetAsync(d_ws, 0, zeroWords * sizeof(int), stream);

    const int eb = (nEdges + 255) / 256;
    const int nb = (nNodes + 255) / 256;

    gin_build1<<<eb, 256, 0, stream>>>(dstArr, nEdges, counts, w1, w2, whf, wlf, wTotal);
    gin_scanA<<<nb, 256, 0, stream>>>(counts, offsets, partials, nNodes);
    gin_scanB<<<nb, 256, 0, stream>>>(offsets, partials, cursor, nb, nNodes, nEdges);
    gin_scatter<<<eb, 256, 0, stream>>>(srcArr, dstArr, nEdges, cursor, ssrc);

    const int lb = (nNodes + TM - 1) / TM;
    const float* hin = x;
    float* bufs[2] = {bufA, bufB};
    for (int L = 0; L < nLayers; ++L) {
        int last = (L == nLayers - 1);
        float* hout = bufs[L & 1];
        gin_layer<<<lb, 256, 0, stream>>>(hin, offsets, ssrc, whf, wlf, 2 * L,
                                          b1 + (size_t)L * 128, b2 + (size_t)L * 128,
                                          hout, batch, gsums, nNodes, last);
        hin = hout;
    }
    gin_pool2<<<nGraphs, 128, 0, stream>>>(gsums, batch, nNodes, wlin, blin, out, nGraphs);
}